// Round 7
// baseline (135.441 us; speedup 1.0000x reference)
//
#include <hip/hip_runtime.h>
#include <math.h>

typedef __attribute__((ext_vector_type(4))) float f32x4;
typedef __attribute__((ext_vector_type(16))) float f32x16;
typedef __attribute__((ext_vector_type(8))) short short8;
typedef __attribute__((ext_vector_type(8))) __bf16 bf16x8;
typedef __attribute__((ext_vector_type(2))) __bf16 bf16x2;
typedef __attribute__((ext_vector_type(2))) unsigned uint32x2;

#define NB 4
#define NS 2048
#define NHID 576
#define NHEADS 9
#define NKVH 3
#define NHD 64
#define NM (NB * NS)      // 8192 rows
#define NQKV 960          // (9 + 3 + 3) * 64
#define NGRP 3            // NHEADS / NKVH

static __device__ __forceinline__ unsigned short f2bf(float f) {
  union { float f; unsigned u; } v; v.f = f;
  unsigned r = v.u + 0x7FFFu + ((v.u >> 16) & 1u);
  return (unsigned short)(r >> 16);
}
static __device__ __forceinline__ unsigned pk2bf(float a, float b) {
  bf16x2 h;
  h.x = (__bf16)a;
  h.y = (__bf16)b;
  return __builtin_bit_cast(unsigned, h);
}
static __device__ __forceinline__ float bf2f(unsigned short h) {
  union { unsigned u; float f; } v; v.u = ((unsigned)h) << 16;
  return v.f;
}
static __device__ __forceinline__ f32x4 mfma16(short8 a, short8 b, f32x4 c) {
  return __builtin_amdgcn_mfma_f32_16x16x32_bf16(
      __builtin_bit_cast(bf16x8, a), __builtin_bit_cast(bf16x8, b), c, 0, 0, 0);
}
static __device__ __forceinline__ f32x16 mfma32(short8 a, short8 b, f32x16 c) {
  return __builtin_amdgcn_mfma_f32_32x32x16_bf16(
      __builtin_bit_cast(bf16x8, a), __builtin_bit_cast(bf16x8, b), c, 0, 0, 0);
}
static __device__ __forceinline__ void gload16(const void* g, void* l) {
  __builtin_amdgcn_global_load_lds(
      (const __attribute__((address_space(1))) void*)g,
      (__attribute__((address_space(3))) void*)l, 16, 0, 0);
}

// ---------------- f32 -> bf16 convert (x) ----------------
__global__ __launch_bounds__(256)
void k_cvt(const float* __restrict__ src, unsigned short* __restrict__ dst, const int n8) {
  const int t = blockIdx.x * 256 + threadIdx.x;
  if (t >= n8) return;
  const f32x4* sp = (const f32x4*)(src + (size_t)t * 8);
  f32x4 a = sp[0], b = sp[1];
  union { short8 v; unsigned short u[8]; } o;
#pragma unroll
  for (int e = 0; e < 4; ++e) { o.u[e] = f2bf(a[e]); o.u[4 + e] = f2bf(b[e]); }
  *(short8*)(dst + (size_t)t * 8) = o.v;
}

// ---------------- transpose + convert: src[R][C] f32 -> dst[c][r] bf16 ----------------
__global__ __launch_bounds__(256)
void k_transpose_cvt(const float* __restrict__ src, unsigned short* __restrict__ dst,
                     const int R, const int C) {
  __shared__ unsigned short tile[64 * 72];
  const int t = threadIdx.x;
  const int r0 = blockIdx.y * 64, c0 = blockIdx.x * 64;
  {
    const int rl = t >> 2, cb = (t & 3) * 16;
    const float* sp = src + (size_t)(r0 + rl) * C + c0 + cb;
#pragma unroll
    for (int jj = 0; jj < 4; ++jj) {
      f32x4 v = *(const f32x4*)(sp + jj * 4);
#pragma unroll
      for (int e = 0; e < 4; ++e) tile[rl * 72 + cb + jj * 4 + e] = f2bf(v[e]);
    }
  }
  __syncthreads();
  {
    const int cl = t >> 2, rb = (t & 3) * 16;
    union { short8 v; unsigned short u[8]; } o0, o1;
#pragma unroll
    for (int jj = 0; jj < 8; ++jj) {
      o0.u[jj] = tile[(rb + jj) * 72 + cl];
      o1.u[jj] = tile[(rb + 8 + jj) * 72 + cl];
    }
    unsigned short* dp = dst + (size_t)(c0 + cl) * R + r0 + rb;
    *(short8*)dp = o0.v;
    *(short8*)(dp + 8) = o1.v;
  }
}

// ---------------- GEMM: C[M][N] = A[M][K](bf16) * Bt[N][K](bf16)^T ----------------
template <int OUT_F32>
__global__ __launch_bounds__(256)
void k_gemm_bt(const unsigned short* __restrict__ A,
               const unsigned short* __restrict__ Bt,
               void* __restrict__ Cv,
               const int M, const int N, const int K) {
  __shared__ unsigned short a_lds[128 * 64];
  __shared__ unsigned short b_lds[128 * 64];
  const int tid = threadIdx.x;
  const int w = tid >> 6, l = tid & 63, g = l >> 4, c = l & 15;
  const int tm = blockIdx.y * 128, tn = blockIdx.x * 128;
  const int wm = w >> 1, wn = w & 1;
  f32x4 acc[4][4] = {};

  for (int k0 = 0; k0 < K; k0 += 64) {
#pragma unroll
    for (int q = 0; q < 4; ++q) {
      const int o = q * 4096 + w * 1024 + l * 16;
      const int row = o >> 7;
      const int wb = (o & 127) ^ ((row & 7) << 4);
      gload16(A + (size_t)(tm + row) * K + k0 + (wb >> 1),
              (void*)(a_lds + ((q * 4096 + w * 1024) >> 1)));
    }
#pragma unroll
    for (int q = 0; q < 4; ++q) {
      const int o = q * 4096 + w * 1024 + l * 16;
      const int row = o >> 7;
      const int wb = (o & 127) ^ ((row & 7) << 4);
      gload16(Bt + (size_t)(tn + row) * K + k0 + (wb >> 1),
              (void*)(b_lds + ((q * 4096 + w * 1024) >> 1)));
    }
    __syncthreads();
#pragma unroll
    for (int dc = 0; dc < 2; ++dc) {
      short8 af[4], bf[4];
#pragma unroll
      for (int mt = 0; mt < 4; ++mt) {
        const int row = wm * 64 + mt * 16 + c;
        const int byt = ((row << 7) + (dc << 6) + (g << 4)) ^ ((row & 7) << 4);
        af[mt] = *(const short8*)((const char*)a_lds + byt);
      }
#pragma unroll
      for (int nt = 0; nt < 4; ++nt) {
        const int row = wn * 64 + nt * 16 + c;
        const int byt = ((row << 7) + (dc << 6) + (g << 4)) ^ ((row & 7) << 4);
        bf[nt] = *(const short8*)((const char*)b_lds + byt);
      }
      __builtin_amdgcn_s_setprio(1);
#pragma unroll
      for (int mt = 0; mt < 4; ++mt)
#pragma unroll
        for (int nt = 0; nt < 4; ++nt)
          acc[mt][nt] = mfma16(af[mt], bf[nt], acc[mt][nt]);
      __builtin_amdgcn_s_setprio(0);
    }
    __syncthreads();
  }

#pragma unroll
  for (int mt = 0; mt < 4; ++mt)
#pragma unroll
    for (int nt = 0; nt < 4; ++nt) {
      const int cc = tn + wn * 64 + nt * 16 + c;
      if (cc < N) {
#pragma unroll
        for (int i = 0; i < 4; ++i) {
          const size_t rr = (size_t)(tm + wm * 64 + mt * 16 + 4 * g + i);
          if (OUT_F32) ((float*)Cv)[rr * N + cc] = acc[mt][nt][i];
          else ((unsigned short*)Cv)[rr * N + cc] = f2bf(acc[mt][nt][i]);
        }
      }
    }
}

// ---------------- RoPE in-place; q scaled by (1/sqrt(HD))*log2(e) for exp2-domain softmax ----------------
__global__ __launch_bounds__(256)
void k_rope(unsigned short* __restrict__ qkv, const float* __restrict__ cosT,
            const float* __restrict__ sinT) {
  const int t = blockIdx.x * 256 + threadIdx.x;
  const int m = t / 48, r = t - m * 48;
  const int hc = r >> 2, qq = r & 3;
  const int s = m & (NS - 1);
  const float qs = (hc < NHEADS) ? 0.18033688f : 1.0f;   // 0.125 * log2(e)
  unsigned short* p = qkv + (size_t)m * NQKV + hc * NHD + qq * 8;
  short8 x1 = *(short8*)p;
  short8 x2 = *(short8*)(p + 32);
  const float* cp = cosT + s * NHD + qq * 8;
  const float* sp = sinT + s * NHD + qq * 8;
  f32x4 c0 = *(const f32x4*)cp, c1 = *(const f32x4*)(cp + 4);
  f32x4 s0 = *(const f32x4*)sp, s1 = *(const f32x4*)(sp + 4);
  float cc[8] = {c0[0], c0[1], c0[2], c0[3], c1[0], c1[1], c1[2], c1[3]};
  float ss[8] = {s0[0], s0[1], s0[2], s0[3], s1[0], s1[1], s1[2], s1[3]};
  union { short8 v; unsigned short u[8]; } o1, o2;
#pragma unroll
  for (int jj = 0; jj < 8; ++jj) {
    float a = bf2f((unsigned short)x1[jj]);
    float bb = bf2f((unsigned short)x2[jj]);
    o1.u[jj] = f2bf((a * cc[jj] - bb * ss[jj]) * qs);
    o2.u[jj] = f2bf((bb * cc[jj] + a * ss[jj]) * qs);
  }
  *(short8*)p = o1.v;
  *(short8*)(p + 32) = o2.v;
}

// ---------------- V^T precompute: vt[(b*NKVH+kh)][d][s] ----------------
__global__ __launch_bounds__(256)
void k_vt(const unsigned short* __restrict__ qkv, unsigned short* __restrict__ vt) {
  __shared__ unsigned short tile[64 * 72];
  const int t = threadIdx.x;
  const int st = blockIdx.x;
  const int by = blockIdx.y;
  const int b = by / NKVH, kh = by - b * NKVH;
  {
    const int sl2 = t >> 2, d0 = (t & 3) * 16;
    const unsigned short* sp = qkv + (size_t)(b * NS + st * 64 + sl2) * NQKV +
                               (NHEADS + NKVH) * NHD + kh * NHD + d0;
    *(short8*)&tile[sl2 * 72 + d0] = *(const short8*)sp;
    *(short8*)&tile[sl2 * 72 + d0 + 8] = *(const short8*)(sp + 8);
  }
  __syncthreads();
  {
    const int dl = t >> 2, s0 = (t & 3) * 16;
    union { short8 v; unsigned short u[8]; } o0, o1;
#pragma unroll
    for (int jj = 0; jj < 8; ++jj) {
      o0.u[jj] = tile[(s0 + jj) * 72 + dl];
      o1.u[jj] = tile[(s0 + 8 + jj) * 72 + dl];
    }
    unsigned short* dp = vt + (size_t)(by * 64 + dl) * NS + st * 64 + s0;
    *(short8*)dp = o0.v;
    *(short8*)(dp + 8) = o1.v;
  }
}

// ---------------- causal GQA flash attention (head-shared K/V, 32x32 MFMA, in-reg P) ----------------
// Block = (b,kh,qt): 6 waves = 3 q-heads x 2 q-halves, all sharing one K/V LDS double-buffer.
// Per staged 64-kv tile: 96 mfma32 (3 heads) amortize one barrier-drain pair (3x fewer
// drains / staged bytes per MFMA vs per-head blocks). grid (12, 32), qt = 31 - y (LPT).
// Wave internals: swapped QK^T (mfma32), in-register softmax (lane + lane^32 hold one
// q-column), P redistributed to PV B-operand with 8 shfl_xor(32). XOR-swizzled LDS.
__global__ __launch_bounds__(384)
void k_attn(const unsigned short* __restrict__ qkv,
            const unsigned short* __restrict__ vt,
            unsigned short* __restrict__ ao) {
  __shared__ unsigned short kv_s[2][2][4096];   // [half][K=0/V=1][64 rows x 64] = 32 KB
  const int tid = threadIdx.x;
  const int w = tid >> 6, l = tid & 63;
  const int q32 = l & 31, hi = l >> 5;
  const int grp = blockIdx.x;                    // b*NKVH + kh
  const int qt = 31 - (int)blockIdx.y;
  const int b = grp / NKVH, kh = grp - b * NKVH;
  const int hq = w >> 1, sub = w & 1;            // head-in-group, q-half
  const int h = kh * NGRP + hq;

  const char* kgb = (const char*)(qkv + (size_t)b * NS * NQKV + NHEADS * NHD + kh * NHD);
  const char* vgb = (const char*)(vt + (size_t)grp * NHD * NS);

  const int lr = l >> 3;                     // 0..7
  const int swz = ((l & 7) ^ lr) << 4;       // pre-swizzled source column byte (staging)
  const int rs = (l & 7) << 4;               // read-side XOR key (row&7 == l&7 for all reads)

  // Q fragments (B-operand of 32x32x16): qf[dck][e] = Q[q][dck*16 + hi*8 + e], pre-scaled
  const char* qp = (const char*)(qkv + (size_t)(b * NS + qt * 64 + sub * 32 + q32) * NQKV + h * NHD);
  short8 qf[4];
#pragma unroll
  for (int dck = 0; dck < 4; ++dck)
    qf[dck] = *(const short8*)(qp + dck * 32 + hi * 16);

  f32x16 ot0 = {}, ot1 = {};      // O^T[d = dt*32 + (reg&3)+8*(reg>>2)+4*hi][q]
  float m = -1e30f, lsum = 0.f;
  const int q_g = qt * 64 + sub * 32 + q32;

  // stage KV tile j: 16 x 1KB chunks (8 K + 8 V) split across 6 waves
#define STAGE(j, half)                                                                     \
  {                                                                                        \
    for (int q = w; q < 16; q += 6) {                                                      \
      const int cc_ = q & 7;                                                               \
      if (q < 8)                                                                           \
        gload16(kgb + (size_t)((j) * 64 + cc_ * 8 + lr) * (NQKV * 2) + swz,                \
                kv_s[half][0] + cc_ * 512);                                                \
      else                                                                                 \
        gload16(vgb + (size_t)(cc_ * 8 + lr) * (NS * 2) + (j) * 128 + swz,                 \
                kv_s[half][1] + cc_ * 512);                                                \
    }                                                                                      \
  }

  STAGE(0, 0);

  for (int j = 0; j <= qt; ++j) {
    __syncthreads();                 // drains tile-j loads
    if (j < qt) STAGE(j + 1, (j + 1) & 1);
    const char* kl = (const char*)kv_s[j & 1][0];
    const char* vl = (const char*)kv_s[j & 1][1];

    // S^T = K Q^T (log2-domain), two 32-kv sub-tiles
    f32x16 st0 = {}, st1 = {};
    __builtin_amdgcn_s_setprio(1);
#pragma unroll
    for (int dck = 0; dck < 4; ++dck) {
      const int colb = (dck * 32 + hi * 16) ^ rs;
      short8 kf0 = *(const short8*)(kl + q32 * 128 + colb);
      short8 kf1 = *(const short8*)(kl + (32 + q32) * 128 + colb);
      st0 = mfma32(kf0, qf[dck], st0);
      st1 = mfma32(kf1, qf[dck], st1);
    }
    __builtin_amdgcn_s_setprio(0);

    // causal mask (diagonal tile only)
    if (j == qt) {
#pragma unroll
      for (int i = 0; i < 16; ++i) {
        const int kvr = (i & 3) + 8 * (i >> 2) + 4 * hi;
        if (j * 64 + kvr > q_g) st0[i] = -1e30f;
        if (j * 64 + 32 + kvr > q_g) st1[i] = -1e30f;
      }
    }

    // tile max: in-lane tree over 32 + 1 shfl_xor(32)
    float pm;
    {
      float a0 = fmaxf(fmaxf(st0[0], st0[1]), fmaxf(st0[2], st0[3]));
      float a1 = fmaxf(fmaxf(st0[4], st0[5]), fmaxf(st0[6], st0[7]));
      float a2 = fmaxf(fmaxf(st0[8], st0[9]), fmaxf(st0[10], st0[11]));
      float a3 = fmaxf(fmaxf(st0[12], st0[13]), fmaxf(st0[14], st0[15]));
      float b0 = fmaxf(fmaxf(st1[0], st1[1]), fmaxf(st1[2], st1[3]));
      float b1 = fmaxf(fmaxf(st1[4], st1[5]), fmaxf(st1[6], st1[7]));
      float b2 = fmaxf(fmaxf(st1[8], st1[9]), fmaxf(st1[10], st1[11]));
      float b3 = fmaxf(fmaxf(st1[12], st1[13]), fmaxf(st1[14], st1[15]));
      pm = fmaxf(fmaxf(fmaxf(a0, a1), fmaxf(a2, a3)),
                 fmaxf(fmaxf(b0, b1), fmaxf(b2, b3)));
      pm = fmaxf(pm, __shfl_xor(pm, 32));
    }

    // defer-max (T13)
    if (!__all(pm <= m + 8.0f)) {
      const float mn = fmaxf(m, pm);
      const float scl = exp2f(m - mn);
      m = mn;
      lsum *= scl;
      ot0 *= scl;
      ot1 *= scl;
    }

    // P = exp2(S - m): 32 exp, sum tree, pack to 16 bf16x2 dwords
    float p0[16], p1[16];
#pragma unroll
    for (int i = 0; i < 16; ++i) { p0[i] = exp2f(st0[i] - m); p1[i] = exp2f(st1[i] - m); }
    {
      float s0 = (p0[0] + p0[1]) + (p0[2] + p0[3]);
      float s1 = (p0[4] + p0[5]) + (p0[6] + p0[7]);
      float s2 = (p0[8] + p0[9]) + (p0[10] + p0[11]);
      float s3 = (p0[12] + p0[13]) + (p0[14] + p0[15]);
      float s4 = (p1[0] + p1[1]) + (p1[2] + p1[3]);
      float s5 = (p1[4] + p1[5]) + (p1[6] + p1[7]);
      float s6 = (p1[8] + p1[9]) + (p1[10] + p1[11]);
      float s7 = (p1[12] + p1[13]) + (p1[14] + p1[15]);
      float rsum = ((s0 + s1) + (s2 + s3)) + ((s4 + s5) + (s6 + s7));
      rsum += __shfl_xor(rsum, 32);
      lsum += rsum;
    }
    unsigned d0[8], d1[8];
#pragma unroll
    for (int r = 0; r < 8; ++r) {
      d0[r] = pk2bf(p0[2 * r], p0[2 * r + 1]);
      d1[r] = pk2bf(p1[2 * r], p1[2 * r + 1]);
    }

    // redistribute P to PV B-operand layout: 8 shfl_xor(32)
    const unsigned xa0 = __shfl_xor(hi ? d0[0] : d0[2], 32);
    const unsigned xb0 = __shfl_xor(hi ? d0[1] : d0[3], 32);
    const unsigned xc0 = __shfl_xor(hi ? d0[4] : d0[6], 32);
    const unsigned xd0 = __shfl_xor(hi ? d0[5] : d0[7], 32);
    const unsigned xa1 = __shfl_xor(hi ? d1[0] : d1[2], 32);
    const unsigned xb1 = __shfl_xor(hi ? d1[1] : d1[3], 32);
    const unsigned xc1 = __shfl_xor(hi ? d1[4] : d1[6], 32);
    const unsigned xd1 = __shfl_xor(hi ? d1[5] : d1[7], 32);
    union U4 { unsigned u[4]; short8 v; };
    U4 t;
    short8 pf00, pf01, pf10, pf11;   // [sub][dcv]
    t.u[0] = hi ? xa0 : d0[0]; t.u[1] = hi ? xb0 : d0[1];
    t.u[2] = hi ? d0[2] : xa0; t.u[3] = hi ? d0[3] : xb0; pf00 = t.v;
    t.u[0] = hi ? xc0 : d0[4]; t.u[1] = hi ? xd0 : d0[5];
    t.u[2] = hi ? d0[6] : xc0; t.u[3] = hi ? d0[7] : xd0; pf01 = t.v;
    t.u[0] = hi ? xa1 : d1[0]; t.u[1] = hi ? xb1 : d1[1];
    t.u[2] = hi ? d1[2] : xa1; t.u[3] = hi ? d1[3] : xb1; pf10 = t.v;
    t.u[0] = hi ? xc1 : d1[4]; t.u[1] = hi ? xd1 : d1[5];
    t.u[2] = hi ? d1[6] : xc1; t.u[3] = hi ? d1[7] : xd1; pf11 = t.v;

    // O^T += V^T P : 8 vf reads + 8 MFMAs
    __builtin_amdgcn_s_setprio(1);
    {
      short8 vf;
      vf = *(const short8*)(vl + q32 * 128 + ((0 + hi * 16) ^ rs));
      ot0 = mfma32(vf, pf00, ot0);
      vf = *(const short8*)(vl + q32 * 128 + ((32 + hi * 16) ^ rs));
      ot0 = mfma32(vf, pf01, ot0);
      vf = *(const short8*)(vl + q32 * 128 + ((64 + hi * 16) ^ rs));
      ot0 = mfma32(vf, pf10, ot0);
      vf = *(const short8*)(vl + q32 * 128 + ((96 + hi * 16) ^ rs));
      ot0 = mfma32(vf, pf11, ot0);
      vf = *(const short8*)(vl + (32 + q32) * 128 + ((0 + hi * 16) ^ rs));
      ot1 = mfma32(vf, pf00, ot1);
      vf = *(const short8*)(vl + (32 + q32) * 128 + ((32 + hi * 16) ^ rs));
      ot1 = mfma32(vf, pf01, ot1);
      vf = *(const short8*)(vl + (32 + q32) * 128 + ((64 + hi * 16) ^ rs));
      ot1 = mfma32(vf, pf10, ot1);
      vf = *(const short8*)(vl + (32 + q32) * 128 + ((96 + hi * 16) ^ rs));
      ot1 = mfma32(vf, pf11, ot1);
    }
    __builtin_amdgcn_s_setprio(0);
  }

  // O^T -> LDS (per-wave 4KB region, swizzled) -> coalesced global write
  __syncthreads();
  {
    char* ol = (char*)kv_s + w * 4096;
    const float inv = __builtin_amdgcn_rcpf(lsum);
#pragma unroll
    for (int rq = 0; rq < 4; ++rq) {
      uint32x2 pk0, pk1;
      pk0.x = pk2bf(ot0[rq * 4 + 0] * inv, ot0[rq * 4 + 1] * inv);
      pk0.y = pk2bf(ot0[rq * 4 + 2] * inv, ot0[rq * 4 + 3] * inv);
      pk1.x = pk2bf(ot1[rq * 4 + 0] * inv, ot1[rq * 4 + 1] * inv);
      pk1.y = pk2bf(ot1[rq * 4 + 2] * inv, ot1[rq * 4 + 3] * inv);
      *(uint32x2*)(ol + q32 * 128 + ((16 * rq + 8 * hi) ^ rs)) = pk0;
      *(uint32x2*)(ol + q32 * 128 + ((64 + 16 * rq + 8 * hi) ^ rs)) = pk1;
    }
  }
  __syncthreads();
  {
    const int rr = tid >> 1, half = tid & 1;     // rr 0..191: head = rr>>6, qrow = rr&63
    const int qrow = rr & 63, head = rr >> 6;
    const char* ol = (const char*)kv_s + (rr >> 5) * 4096 + (rr & 31) * 128;
    const int rk = (rr & 7) << 4;
    short8 v0 = *(const short8*)(ol + ((half * 64 + 0) ^ rk));
    short8 v1 = *(const short8*)(ol + ((half * 64 + 16) ^ rk));
    short8 v2 = *(const short8*)(ol + ((half * 64 + 32) ^ rk));
    short8 v3 = *(const short8*)(ol + ((half * 64 + 48) ^ rk));
    char* aop = (char*)(ao + (size_t)(b * NS + qt * 64 + qrow) * (NHEADS * NHD) +
                        (kh * NGRP + head) * NHD + half * 32);
    *(short8*)aop = v0;
    *(short8*)(aop + 16) = v1;
    *(short8*)(aop + 32) = v2;
    *(short8*)(aop + 48) = v3;
  }
#undef STAGE
}

extern "C" void kernel_launch(void* const* d_in, const int* in_sizes, int n_in,
                              void* d_out, int out_size, void* d_ws, size_t ws_size,
                              hipStream_t stream) {
  const float* x = (const float*)d_in[0];
  const float* cosT = (const float*)d_in[1];
  const float* sinT = (const float*)d_in[2];
  const float* Wq = (const float*)d_in[4];
  const float* Wk = (const float*)d_in[5];
  const float* Wv = (const float*)d_in[6];
  const float* Wo = (const float*)d_in[7];

  unsigned short* xb = (unsigned short*)d_ws;                      // [8192][576]
  unsigned short* wqkvT = xb + (size_t)NM * NHID;                  // [960][576]
  unsigned short* woT = wqkvT + (size_t)NQKV * NHID;               // [576][576]
  unsigned short* qkv = woT + (size_t)NHID * NHID;                 // [8192][960]
  unsigned short* vt = qkv + (size_t)NM * NQKV;                    // [12][64][2048]
  unsigned short* ao = vt + (size_t)NB * NKVH * NHD * NS;          // [8192][576]

  k_cvt<<<dim3((NM * NHID / 8 + 255) / 256), 256, 0, stream>>>(x, xb, NM * NHID / 8);
  k_transpose_cvt<<<dim3(9, 9), 256, 0, stream>>>(Wq, wqkvT, NHID, NHID);
  k_transpose_cvt<<<dim3(3, 9), 256, 0, stream>>>(Wk, wqkvT + (size_t)576 * 576, NHID, 192);
  k_transpose_cvt<<<dim3(3, 9), 256, 0, stream>>>(Wv, wqkvT + (size_t)768 * 576, NHID, 192);
  k_transpose_cvt<<<dim3(9, 9), 256, 0, stream>>>(Wo, woT, NHID, NHID);
  k_gemm_bt<0><<<dim3((NQKV + 127) / 128, NM / 128), 256, 0, stream>>>(xb, wqkvT, (void*)qkv, NM, NQKV, NHID);
  k_rope<<<dim3(NM * 48 / 256), 256, 0, stream>>>(qkv, cosT, sinT);
  k_vt<<<dim3(NS / 64, NB * NKVH), 256, 0, stream>>>(qkv, vt);
  k_attn<<<dim3(NB * NKVH, NS / 64), 384, 0, stream>>>(qkv, vt, ao);
  k_gemm_bt<1><<<dim3((NHID + 127) / 128, NM / 128), 256, 0, stream>>>(ao, woT, d_out, NM, NHID, NHID);
}

// Round 8
// 105.983 us; speedup vs baseline: 1.2779x; 1.2779x over previous
//
#include <hip/hip_runtime.h>
#include <math.h>

typedef __attribute__((ext_vector_type(4))) float f32x4;
typedef __attribute__((ext_vector_type(8))) short short8;
typedef __attribute__((ext_vector_type(8))) __bf16 bf16x8;
typedef __attribute__((ext_vector_type(2))) __bf16 bf16x2;
typedef __attribute__((ext_vector_type(2))) unsigned uint32x2;

#define NB 4
#define NS 2048
#define NHID 576
#define NHEADS 9
#define NKVH 3
#define NHD 64
#define NM (NB * NS)      // 8192 rows
#define NQKV 960          // (9 + 3 + 3) * 64
#define NGRP 3            // NHEADS / NKVH
#define QSC 0.18033688f   // (1/sqrt(64)) * log2(e)

static __device__ __forceinline__ unsigned short f2bf(float f) {
  union { float f; unsigned u; } v; v.f = f;
  unsigned r = v.u + 0x7FFFu + ((v.u >> 16) & 1u);
  return (unsigned short)(r >> 16);
}
static __device__ __forceinline__ unsigned pk2bf(float a, float b) {
  bf16x2 h;
  h.x = (__bf16)a;
  h.y = (__bf16)b;
  return __builtin_bit_cast(unsigned, h);
}
static __device__ __forceinline__ f32x4 mfma16(short8 a, short8 b, f32x4 c) {
  return __builtin_amdgcn_mfma_f32_16x16x32_bf16(
      __builtin_bit_cast(bf16x8, a), __builtin_bit_cast(bf16x8, b), c, 0, 0, 0);
}
static __device__ __forceinline__ void gload16(const void* g, void* l) {
  __builtin_amdgcn_global_load_lds(
      (const __attribute__((address_space(1))) void*)g,
      (__attribute__((address_space(3))) void*)l, 16, 0, 0);
}

// ---------------- f32 -> bf16 convert (x) ----------------
__global__ __launch_bounds__(256)
void k_cvt(const float* __restrict__ src, unsigned short* __restrict__ dst, const int n8) {
  const int t = blockIdx.x * 256 + threadIdx.x;
  if (t >= n8) return;
  const f32x4* sp = (const f32x4*)(src + (size_t)t * 8);
  f32x4 a = sp[0], b = sp[1];
  union { short8 v; unsigned short u[8]; } o;
#pragma unroll
  for (int e = 0; e < 4; ++e) { o.u[e] = f2bf(a[e]); o.u[4 + e] = f2bf(b[e]); }
  *(short8*)(dst + (size_t)t * 8) = o.v;
}

// ---------------- transpose + convert: src[R][C] f32 -> dst[c][r] bf16 ----------------
__global__ __launch_bounds__(256)
void k_transpose_cvt(const float* __restrict__ src, unsigned short* __restrict__ dst,
                     const int R, const int C) {
  __shared__ unsigned short tile[64 * 72];
  const int t = threadIdx.x;
  const int r0 = blockIdx.y * 64, c0 = blockIdx.x * 64;
  {
    const int rl = t >> 2, cb = (t & 3) * 16;
    const float* sp = src + (size_t)(r0 + rl) * C + c0 + cb;
#pragma unroll
    for (int jj = 0; jj < 4; ++jj) {
      f32x4 v = *(const f32x4*)(sp + jj * 4);
#pragma unroll
      for (int e = 0; e < 4; ++e) tile[rl * 72 + cb + jj * 4 + e] = f2bf(v[e]);
    }
  }
  __syncthreads();
  {
    const int cl = t >> 2, rb = (t & 3) * 16;
    union { short8 v; unsigned short u[8]; } o0, o1;
#pragma unroll
    for (int jj = 0; jj < 8; ++jj) {
      o0.u[jj] = tile[(rb + jj) * 72 + cl];
      o1.u[jj] = tile[(rb + 8 + jj) * 72 + cl];
    }
    unsigned short* dp = dst + (size_t)(c0 + cl) * R + r0 + rb;
    *(short8*)dp = o0.v;
    *(short8*)(dp + 8) = o1.v;
  }
}

// ---------------- GEMM: C[M][N] = A[M][K](bf16) * Bt[N][K](bf16)^T ----------------
// BM=128 BN=128 BK=64, 4 waves (2x2 of 64x64), LDS double-buffered, counted-vmcnt
// schedule (loads never drained to 0 in the loop), dual raw barrier per K-step.
// MODE 0: bf16 out + fused RoPE (cols < 768; q cols < 576 also scaled by QSC).
// MODE 1: f32 out plain.
template <int MODE>
__global__ __launch_bounds__(256)
void k_gemm_bt(const unsigned short* __restrict__ A,
               const unsigned short* __restrict__ Bt,
               void* __restrict__ Cv,
               const float* __restrict__ cosT,
               const float* __restrict__ sinT,
               const int M, const int N, const int K) {
  __shared__ unsigned short a_lds[2][128 * 64];  // 32 KB
  __shared__ unsigned short b_lds[2][128 * 64];  // 32 KB
  const int tid = threadIdx.x;
  const int w = tid >> 6, l = tid & 63, g = l >> 4, c = l & 15;
  const int tm = blockIdx.y * 128, tn = blockIdx.x * 128;
  const int wm = w >> 1, wn = w & 1;
  f32x4 acc[4][4] = {};
  const int nk = K >> 6;

#define GSTAGE(k0, half)                                                   \
  {                                                                        \
    _Pragma("unroll")                                                      \
    for (int q = 0; q < 4; ++q) {                                          \
      const int o = q * 4096 + w * 1024 + l * 16;                          \
      const int row = o >> 7;                                              \
      const int wb = (o & 127) ^ ((row & 7) << 4);                         \
      gload16(A + (size_t)(tm + row) * K + (k0) + (wb >> 1),               \
              (void*)(a_lds[half] + ((q * 4096 + w * 1024) >> 1)));        \
      gload16(Bt + (size_t)(tn + row) * K + (k0) + (wb >> 1),              \
              (void*)(b_lds[half] + ((q * 4096 + w * 1024) >> 1)));        \
    }                                                                      \
  }

  GSTAGE(0, 0);

  for (int k = 0; k < nk; ++k) {
    if (k + 1 < nk) {
      GSTAGE((k + 1) << 6, (k + 1) & 1);
      asm volatile("s_waitcnt vmcnt(8)" ::: "memory");
    } else {
      asm volatile("s_waitcnt vmcnt(0)" ::: "memory");
    }
    __builtin_amdgcn_s_barrier();
    __builtin_amdgcn_sched_barrier(0);
    const char* al = (const char*)a_lds[k & 1];
    const char* bl = (const char*)b_lds[k & 1];
#pragma unroll
    for (int dc = 0; dc < 2; ++dc) {
      short8 af[4], bf[4];
#pragma unroll
      for (int mt = 0; mt < 4; ++mt) {
        const int row = wm * 64 + mt * 16 + c;
        const int byt = ((row << 7) + (dc << 6) + (g << 4)) ^ ((row & 7) << 4);
        af[mt] = *(const short8*)(al + byt);
      }
#pragma unroll
      for (int nt = 0; nt < 4; ++nt) {
        const int row = wn * 64 + nt * 16 + c;
        const int byt = ((row << 7) + (dc << 6) + (g << 4)) ^ ((row & 7) << 4);
        bf[nt] = *(const short8*)(bl + byt);
      }
      __builtin_amdgcn_s_setprio(1);
#pragma unroll
      for (int mt = 0; mt < 4; ++mt)
#pragma unroll
        for (int nt = 0; nt < 4; ++nt)
          acc[mt][nt] = mfma16(af[mt], bf[nt], acc[mt][nt]);
      __builtin_amdgcn_s_setprio(0);
    }
    __builtin_amdgcn_sched_barrier(0);
    __builtin_amdgcn_s_barrier();
  }
#undef GSTAGE

  if (MODE == 1) {
#pragma unroll
    for (int mt = 0; mt < 4; ++mt)
#pragma unroll
      for (int nt = 0; nt < 4; ++nt) {
        const int cc = tn + wn * 64 + nt * 16 + c;
        if (cc < N) {
#pragma unroll
          for (int i = 0; i < 4; ++i) {
            const size_t rr = (size_t)(tm + wm * 64 + mt * 16 + 4 * g + i);
            ((float*)Cv)[rr * N + cc] = acc[mt][nt][i];
          }
        }
      }
  } else if (tn < 768) {
    // fused RoPE: within-head col d = nt*16+c; pairs (nt, nt+2) = (d, d+32).
    // cos[s][d] == cos[s][d+32] (duplicated table) -> one cos/sin load per pair.
    const float qs = (tn + wn * 64) < 576 ? QSC : 1.0f;
    unsigned short* Cp = (unsigned short*)Cv;
#pragma unroll
    for (int mt = 0; mt < 4; ++mt)
#pragma unroll
      for (int i = 0; i < 4; ++i) {
        const int rr = tm + wm * 64 + mt * 16 + 4 * g + i;
        const int s = rr & (NS - 1);
        const float* cb = cosT + (size_t)s * NHD;
        const float* sb = sinT + (size_t)s * NHD;
#pragma unroll
        for (int p = 0; p < 2; ++p) {
          const float cn = cb[p * 16 + c];
          const float sn = sb[p * 16 + c];
          const float lo = acc[mt][p][i];
          const float hi = acc[mt][p + 2][i];
          const size_t base = (size_t)rr * N + tn + wn * 64 + p * 16 + c;
          Cp[base] = f2bf((lo * cn - hi * sn) * qs);
          Cp[base + 32] = f2bf((hi * cn + lo * sn) * qs);
        }
      }
  } else {
    unsigned short* Cp = (unsigned short*)Cv;
#pragma unroll
    for (int mt = 0; mt < 4; ++mt)
#pragma unroll
      for (int nt = 0; nt < 4; ++nt) {
        const int cc = tn + wn * 64 + nt * 16 + c;
        if (cc < N) {
#pragma unroll
          for (int i = 0; i < 4; ++i) {
            const size_t rr = (size_t)(tm + wm * 64 + mt * 16 + 4 * g + i);
            Cp[rr * N + cc] = f2bf(acc[mt][nt][i]);
          }
        }
      }
  }
}

// ---------------- V^T precompute: vt[(b*NKVH+kh)][d][s] ----------------
__global__ __launch_bounds__(256)
void k_vt(const unsigned short* __restrict__ qkv, unsigned short* __restrict__ vt) {
  __shared__ unsigned short tile[64 * 72];
  const int t = threadIdx.x;
  const int st = blockIdx.x;
  const int by = blockIdx.y;
  const int b = by / NKVH, kh = by - b * NKVH;
  {
    const int sl2 = t >> 2, d0 = (t & 3) * 16;
    const unsigned short* sp = qkv + (size_t)(b * NS + st * 64 + sl2) * NQKV +
                               (NHEADS + NKVH) * NHD + kh * NHD + d0;
    *(short8*)&tile[sl2 * 72 + d0] = *(const short8*)sp;
    *(short8*)&tile[sl2 * 72 + d0 + 8] = *(const short8*)(sp + 8);
  }
  __syncthreads();
  {
    const int dl = t >> 2, s0 = (t & 3) * 16;
    union { short8 v; unsigned short u[8]; } o0, o1;
#pragma unroll
    for (int jj = 0; jj < 8; ++jj) {
      o0.u[jj] = tile[(s0 + jj) * 72 + dl];
      o1.u[jj] = tile[(s0 + 8 + jj) * 72 + dl];
    }
    unsigned short* dp = vt + (size_t)(by * 64 + dl) * NS + st * 64 + s0;
    *(short8*)dp = o0.v;
    *(short8*)(dp + 8) = o1.v;
  }
}

// ---------------- causal GQA flash attention (R3 internals + counted-vmcnt schedule) ----------------
// grid = (36 bh, 32 qtIdx), qt = 31 - qtIdx (longest-first). 4 waves x 16 q-rows.
// KV tiles of 64 rows, double-buffered. Loop: STAGE(j+1); vmcnt(4); barrier; compute(j);
// barrier — prefetch loads stay in flight across barriers (never drained to 0 mid-loop).
// LDS XOR-swizzle phys = log ^ ((row&7)<<4), rows 128B.
__global__ __launch_bounds__(256)
void k_attn(const unsigned short* __restrict__ qkv,
            const unsigned short* __restrict__ vt,
            unsigned short* __restrict__ ao) {
  __shared__ unsigned short kv_s[2][2][4096];   // [half][K=0/V=1][64 rows x 64] = 32 KB
  __shared__ unsigned short p_s[4][1024];       // per-wave P^T [16 q][64 kv] = 8 KB
  const int tid = threadIdx.x;
  const int w = tid >> 6, l = tid & 63, g = l >> 4, c = l & 15;
  const int bh = blockIdx.x;
  const int qt = 31 - (int)blockIdx.y;
  const int b = bh / NHEADS, h = bh - b * NHEADS, kh = h / NGRP;

  const char* kgb = (const char*)(qkv + (size_t)b * NS * NQKV + NHEADS * NHD + kh * NHD);
  const char* vgb = (const char*)(vt + (size_t)(b * NKVH + kh) * NHD * NS);

  const int lr = l >> 3;                     // 0..7
  const int swz = ((l & 7) ^ lr) << 4;       // pre-swizzled source column byte
  const int r0 = 16 * w + lr;                // this lane's staging row (and +8)
  const int cs = (c & 7) << 4;               // read-side XOR key

  // Q fragments (B-operand): lane holds Q[q=w*16+c][d = dc*32 + g*8 + j], pre-scaled by QSC
  const size_t qrow = (size_t)(b * NS + qt * 64 + w * 16 + c) * NQKV + h * NHD;
  const short8 qf0 = *(const short8*)(qkv + qrow + g * 8);
  const short8 qf1 = *(const short8*)(qkv + qrow + 32 + g * 8);

  const short8 ones = {0x3F80, 0x3F80, 0x3F80, 0x3F80, 0x3F80, 0x3F80, 0x3F80, 0x3F80};

  f32x4 ot[4] = {};            // O^T: lane holds O^T[d=nt*16+4g+i][q=w*16+c]
  f32x4 lacc = {};             // row-sum accumulator via mfma(ones, P)
  float m = -1e30f;
  const int q_g = qt * 64 + w * 16 + c;

#define STAGE(j, half)                                                          \
  {                                                                             \
    unsigned short* kl_ = kv_s[half][0];                                        \
    unsigned short* vl_ = kv_s[half][1];                                        \
    gload16(kgb + (size_t)((j) * 64 + r0) * (NQKV * 2) + swz, kl_ + 16 * w * 64);       \
    gload16(kgb + (size_t)((j) * 64 + r0 + 8) * (NQKV * 2) + swz, kl_ + (16 * w + 8) * 64); \
    gload16(vgb + (size_t)r0 * (NS * 2) + (j) * 128 + swz, vl_ + 16 * w * 64);          \
    gload16(vgb + (size_t)(r0 + 8) * (NS * 2) + (j) * 128 + swz, vl_ + (16 * w + 8) * 64); \
  }

  STAGE(0, 0);

  for (int j = 0; j <= qt; ++j) {
    if (j < qt) {
      STAGE(j + 1, (j + 1) & 1);
      asm volatile("s_waitcnt vmcnt(4)" ::: "memory");
    } else {
      asm volatile("s_waitcnt vmcnt(0)" ::: "memory");
    }
    __builtin_amdgcn_s_barrier();
    __builtin_amdgcn_sched_barrier(0);
    const char* kl = (const char*)kv_s[j & 1][0];
    const char* vl = (const char*)kv_s[j & 1][1];

    // S^T = K Q^T (log2-domain): lane holds S^T[kv=j*64+nt*16+4g+i][q=c]
    f32x4 st[4] = {};
#pragma unroll
    for (int dc = 0; dc < 2; ++dc) {
      const int col = (dc * 64 + g * 16) ^ cs;
      const short8 qf = dc ? qf1 : qf0;
#pragma unroll
      for (int nt = 0; nt < 4; ++nt) {
        short8 kf = *(const short8*)(kl + (nt * 16 + c) * 128 + col);
        st[nt] = mfma16(kf, qf, st[nt]);
      }
    }

    // causal mask: only the diagonal tile straddles
    if (j == qt) {
#pragma unroll
      for (int nt = 0; nt < 4; ++nt)
#pragma unroll
        for (int i = 0; i < 4; ++i) {
          const int kvg = j * 64 + nt * 16 + 4 * g + i;
          if (kvg > q_g) st[nt][i] = -1e30f;
        }
    }

    // tile max (per lane = one q column)
    float m0 = fmaxf(fmaxf(st[0][0], st[0][1]), st[0][2]);
    float m1 = fmaxf(fmaxf(st[0][3], st[1][0]), st[1][1]);
    float m2 = fmaxf(fmaxf(st[1][2], st[1][3]), st[2][0]);
    float m3 = fmaxf(fmaxf(st[2][1], st[2][2]), st[2][3]);
    float m4 = fmaxf(fmaxf(st[3][0], st[3][1]), st[3][2]);
    float pm = fmaxf(fmaxf(fmaxf(m0, m1), fmaxf(m2, m3)), fmaxf(m4, st[3][3]));
    pm = fmaxf(pm, __shfl_xor(pm, 16));
    pm = fmaxf(pm, __shfl_xor(pm, 32));

    // defer-max (T13): rescale only when tile max grows past threshold (log2 units)
    if (!__all(pm <= m + 8.0f)) {
      const float scl = exp2f(m - pm);
      m = pm;
      lacc *= scl;
#pragma unroll
      for (int nt = 0; nt < 4; ++nt) ot[nt] *= scl;
    }

    // P = exp2(S - m); pack (v_cvt_pk) and write P^T rows to per-wave LDS
    {
      char* pw = (char*)p_s[w];
#pragma unroll
      for (int nt = 0; nt < 4; ++nt) {
        float p0 = exp2f(st[nt][0] - m);
        float p1 = exp2f(st[nt][1] - m);
        float p2 = exp2f(st[nt][2] - m);
        float p3 = exp2f(st[nt][3] - m);
        uint32x2 pk;
        pk.x = pk2bf(p0, p1);
        pk.y = pk2bf(p2, p3);
        *(uint32x2*)(pw + c * 128 + ((nt * 32 + g * 8) ^ cs)) = pk;
      }
      // O^T += V^T P^T ; lacc += ones * P^T (row-sums via matrix pipe)
#pragma unroll
      for (int dc = 0; dc < 2; ++dc) {
        const int col = (dc * 64 + g * 16) ^ cs;
        short8 pf = *(const short8*)(pw + c * 128 + col);
        lacc = mfma16(ones, pf, lacc);
#pragma unroll
        for (int nt = 0; nt < 4; ++nt) {
          short8 vf = *(const short8*)(vl + (nt * 16 + c) * 128 + col);
          ot[nt] = mfma16(vf, pf, ot[nt]);
        }
      }
    }
    __builtin_amdgcn_sched_barrier(0);
    __builtin_amdgcn_s_barrier();
  }

  // O^T -> LDS (swizzled) -> coalesced global write
  {
    char* ol = (char*)kv_s[0][0];
    const float inv = __builtin_amdgcn_rcpf(lacc[0]);
#pragma unroll
    for (int nt = 0; nt < 4; ++nt) {
      uint32x2 pk;
      pk.x = pk2bf(ot[nt][0] * inv, ot[nt][1] * inv);
      pk.y = pk2bf(ot[nt][2] * inv, ot[nt][3] * inv);
      *(uint32x2*)(ol + (w * 16 + c) * 128 + ((nt * 32 + g * 8) ^ cs)) = pk;
    }
  }
  __syncthreads();
  {
    const char* ol = (const char*)kv_s[0][0];
    const int rr = tid >> 2, cb = tid & 3;
    const int rk = (rr & 7) << 4;
    short8 v0 = *(const short8*)(ol + rr * 128 + ((cb * 32) ^ rk));
    short8 v1 = *(const short8*)(ol + rr * 128 + ((cb * 32 + 16) ^ rk));
    char* aop = (char*)(ao + (size_t)(b * NS + qt * 64 + rr) * (NHEADS * NHD) + h * NHD + cb * 16);
    *(short8*)aop = v0;
    *(short8*)(aop + 16) = v1;
  }
#undef STAGE
}

extern "C" void kernel_launch(void* const* d_in, const int* in_sizes, int n_in,
                              void* d_out, int out_size, void* d_ws, size_t ws_size,
                              hipStream_t stream) {
  const float* x = (const float*)d_in[0];
  const float* cosT = (const float*)d_in[1];
  const float* sinT = (const float*)d_in[2];
  const float* Wq = (const float*)d_in[4];
  const float* Wk = (const float*)d_in[5];
  const float* Wv = (const float*)d_in[6];
  const float* Wo = (const float*)d_in[7];

  unsigned short* xb = (unsigned short*)d_ws;                      // [8192][576]
  unsigned short* wqkvT = xb + (size_t)NM * NHID;                  // [960][576]
  unsigned short* woT = wqkvT + (size_t)NQKV * NHID;               // [576][576]
  unsigned short* qkv = woT + (size_t)NHID * NHID;                 // [8192][960]
  unsigned short* vt = qkv + (size_t)NM * NQKV;                    // [12][64][2048]
  unsigned short* ao = vt + (size_t)NB * NKVH * NHD * NS;          // [8192][576]

  k_cvt<<<dim3((NM * NHID / 8 + 255) / 256), 256, 0, stream>>>(x, xb, NM * NHID / 8);
  k_transpose_cvt<<<dim3(9, 9), 256, 0, stream>>>(Wq, wqkvT, NHID, NHID);
  k_transpose_cvt<<<dim3(3, 9), 256, 0, stream>>>(Wk, wqkvT + (size_t)576 * 576, NHID, 192);
  k_transpose_cvt<<<dim3(3, 9), 256, 0, stream>>>(Wv, wqkvT + (size_t)768 * 576, NHID, 192);
  k_transpose_cvt<<<dim3(9, 9), 256, 0, stream>>>(Wo, woT, NHID, NHID);
  // QKV projection with fused RoPE (+ q pre-scale) in the epilogue
  k_gemm_bt<0><<<dim3((NQKV + 127) / 128, NM / 128), 256, 0, stream>>>(
      xb, wqkvT, (void*)qkv, cosT, sinT, NM, NQKV, NHID);
  k_vt<<<dim3(NS / 64, NB * NKVH), 256, 0, stream>>>(qkv, vt);
  k_attn<<<dim3(NB * NHEADS, NS / 64), 256, 0, stream>>>(qkv, vt, ao);
  k_gemm_bt<1><<<dim3((NHID + 127) / 128, NM / 128), 256, 0, stream>>>(
      ao, woT, d_out, nullptr, nullptr, NM, NHID, NHID);
}